// Round 1
// baseline (83.148 us; speedup 1.0000x reference)
//
#include <hip/hip_runtime.h>

#define B 8
#define H 256
#define W 512
#define C 16
#define FIL 16
#define NP 8
#define PH 32      // H/NP
#define W2 256     // W/2
#define POOL_ELEMS (B*NP*W2*C)   // 327680 floats

// ---------------- Kernel 1: average pool (32x2) ----------------
// grid = B*NP blocks, 256 threads. Block (b,i) reduces 32 input rows of
// 8192 floats into pooled row [256][16].
__global__ __launch_bounds__(256) void pool_kernel(const float* __restrict__ fm,
                                                   float* __restrict__ P) {
    int blk = blockIdx.x;
    int b = blk >> 3, i = blk & 7;
    int t = threadIdx.x;
    __shared__ float s[W * C];           // 8192 floats = 32 KB
    float4 acc[8];
#pragma unroll
    for (int k = 0; k < 8; ++k) acc[k] = make_float4(0.f, 0.f, 0.f, 0.f);
    const float4* src = (const float4*)(fm + (size_t)(b * H + i * PH) * (W * C));
    for (int hh = 0; hh < PH; ++hh) {
        const float4* row = src + hh * (W * C / 4);
#pragma unroll
        for (int k = 0; k < 8; ++k) {
            float4 v = row[t + k * 256];
            acc[k].x += v.x; acc[k].y += v.y; acc[k].z += v.z; acc[k].w += v.w;
        }
    }
#pragma unroll
    for (int k = 0; k < 8; ++k) ((float4*)s)[t + k * 256] = acc[k];
    __syncthreads();
    float* out = P + (size_t)(b * NP + i) * (W2 * C);
    for (int idx = t; idx < W2 * C; idx += 256) {
        int j = idx >> 4, c = idx & 15;
        out[idx] = (s[j * 32 + c] + s[j * 32 + 16 + c]) * (1.0f / 64.0f);
    }
}

// ---------------- Kernel 2: masked 5x5 conv (rows 0,4 only), row + col ----
// grid = B*NP blocks, 512 threads. t<256: row_op for j=t. t>=256: col_op.
__global__ __launch_bounds__(512) void conv_kernel(const float* __restrict__ P,
                                                   const float* __restrict__ kern,
                                                   const float* __restrict__ bias,
                                                   float* __restrict__ ROW,
                                                   float* __restrict__ COL) {
    int blk = blockIdx.x;
    int b = blk >> 3, i = blk & 7;
    int t = threadIdx.x;
    __shared__ float K0[5 * C * FIL];    // kernel row r=0
    __shared__ float K4[5 * C * FIL];    // kernel row r=4
    for (int idx = t; idx < 5 * C * FIL; idx += 512) {
        K0[idx] = kern[idx];                     // r=0 at offset 0
        K4[idx] = kern[4 * 5 * C * FIL + idx];   // r=4
    }
    __syncthreads();
    int j = t & 255;
    const float* Pb = P + (size_t)b * (NP * W2 * C);
    float acc[FIL];
#pragma unroll
    for (int f = 0; f < FIL; ++f) acc[f] = bias[f];

    if (t < 256) {
        // row_op: rows i-2, i+2 of pooled; cols j+s-2; K[rr][s]
#pragma unroll
        for (int rr = 0; rr < 2; ++rr) {
            int ii = i + (rr ? 2 : -2);
            if (ii < 0 || ii >= NP) continue;
            const float* Kr = rr ? K4 : K0;
            for (int s = 0; s < 5; ++s) {
                int jj = j + s - 2;
                if (jj < 0 || jj >= W2) continue;
                const float* p = Pb + (size_t)(ii * W2 + jj) * C;
                for (int c = 0; c < C; ++c) {
                    float pv = p[c];
                    const float* kk = Kr + (s * C + c) * FIL;
#pragma unroll
                    for (int f = 0; f < FIL; ++f) acc[f] = fmaf(pv, kk[f], acc[f]);
                }
            }
        }
        float* o = ROW + ((size_t)(b * NP + i) * W2 + j) * FIL;
#pragma unroll
        for (int f = 0; f < FIL; ++f) o[f] = fmaxf(acc[f], 0.0f);
    } else {
        // col_op: rows i+s-2; cols j-2, j+2; K[rr][s]
        for (int s = 0; s < 5; ++s) {
            int ii = i + s - 2;
            if (ii < 0 || ii >= NP) continue;
#pragma unroll
            for (int rr = 0; rr < 2; ++rr) {
                int jj = j + (rr ? 2 : -2);
                if (jj < 0 || jj >= W2) continue;
                const float* Kr = rr ? K4 : K0;
                const float* p = Pb + (size_t)(ii * W2 + jj) * C;
                for (int c = 0; c < C; ++c) {
                    float pv = p[c];
                    const float* kk = Kr + (s * C + c) * FIL;
#pragma unroll
                    for (int f = 0; f < FIL; ++f) acc[f] = fmaf(pv, kk[f], acc[f]);
                }
            }
        }
        float* o = COL + ((size_t)(b * NP + i) * W2 + j) * FIL;
#pragma unroll
        for (int f = 0; f < FIL; ++f) o[f] = fmaxf(acc[f], 0.0f);
    }
}

// ---------------- Kernel 3: bilinear upsample + diff + concat -------------
// grid = B*H blocks, 256 threads; one output row [W][48] per block.
__global__ __launch_bounds__(256) void up_kernel(const float* __restrict__ fm,
                                                 const float* __restrict__ ROW,
                                                 const float* __restrict__ COL,
                                                 float* __restrict__ out) {
    int blk = blockIdx.x;
    int b = blk >> 8, h = blk & 255;
    int t = threadIdx.x;
    __shared__ float Rs[W2 * C];   // H-lerped row_op row
    __shared__ float Cs[W2 * C];   // H-lerped col_op row

    float sh = (h + 0.5f) * (1.0f / 32.0f) - 0.5f;
    float flh = floorf(sh);
    float fh = sh - flh;
    int i0 = (int)flh;
    int i1 = min(i0 + 1, NP - 1);
    i0 = max(i0, 0);
    float wa = 1.0f - fh, wb = fh;

    const float4* r0 = (const float4*)(ROW + (size_t)(b * NP + i0) * (W2 * C));
    const float4* r1 = (const float4*)(ROW + (size_t)(b * NP + i1) * (W2 * C));
    const float4* c0 = (const float4*)(COL + (size_t)(b * NP + i0) * (W2 * C));
    const float4* c1 = (const float4*)(COL + (size_t)(b * NP + i1) * (W2 * C));
#pragma unroll
    for (int k = 0; k < 4; ++k) {
        int idx = t + k * 256;
        float4 a = r0[idx], bv = r1[idx];
        ((float4*)Rs)[idx] = make_float4(wa * a.x + wb * bv.x, wa * a.y + wb * bv.y,
                                         wa * a.z + wb * bv.z, wa * a.w + wb * bv.w);
        float4 ca = c0[idx], cb = c1[idx];
        ((float4*)Cs)[idx] = make_float4(wa * ca.x + wb * cb.x, wa * ca.y + wb * cb.y,
                                         wa * ca.z + wb * cb.z, wa * ca.w + wb * cb.w);
    }
    __syncthreads();

    const float4* fmr = (const float4*)(fm + (size_t)(b * H + h) * (W * C));
    float4* orow = (float4*)(out + (size_t)(b * H + h) * (W * 48));
    for (int slot = t; slot < W * 12; slot += 256) {
        int p = slot / 12;
        int q = slot - p * 12;
        int cc = (q & 3) * 4;
        float4 v = fmr[p * 4 + (q & 3)];
        if (q >= 4) {
            float sw = 0.5f * p - 0.25f;
            float flw = floorf(sw);
            float fw = sw - flw;
            int j0i = max((int)flw, 0);
            int j1i = min((int)flw + 1, W2 - 1);
            const float* S = (q < 8) ? Rs : Cs;
            const float* A  = S + j0i * 16 + cc;
            const float* Bv = S + j1i * 16 + cc;
            float iw = 1.0f - fw;
            v.x -= iw * A[0] + fw * Bv[0];
            v.y -= iw * A[1] + fw * Bv[1];
            v.z -= iw * A[2] + fw * Bv[2];
            v.w -= iw * A[3] + fw * Bv[3];
        }
        orow[slot] = v;
    }
}

extern "C" void kernel_launch(void* const* d_in, const int* in_sizes, int n_in,
                              void* d_out, int out_size, void* d_ws, size_t ws_size,
                              hipStream_t stream) {
    const float* fm   = (const float*)d_in[0];
    const float* kern = (const float*)d_in[1];
    const float* bias = (const float*)d_in[2];
    float* out = (float*)d_out;
    float* P   = (float*)d_ws;
    float* ROW = P + POOL_ELEMS;
    float* COL = ROW + POOL_ELEMS;

    pool_kernel<<<B * NP, 256, 0, stream>>>(fm, P);
    conv_kernel<<<B * NP, 512, 0, stream>>>(P, kern, bias, ROW, COL);
    up_kernel<<<B * H, 256, 0, stream>>>(fm, ROW, COL, out);
}

// Round 3
// 72.293 us; speedup vs baseline: 1.1502x; 1.1502x over previous
//
#include <hip/hip_runtime.h>

#define B 8
#define H 256
#define W 512
#define C 16
#define FIL 16
#define NP 8
#define PH 32      // H/NP
#define W2 256     // W/2
#define CH 8       // width chunks for pool kernel
#define POOL_ELEMS (B*NP*W2*C)   // 327680 floats

typedef float f32x4 __attribute__((ext_vector_type(4)));

// ---------------- Kernel 1: average pool (32x2) ----------------
// grid = B*NP*CH = 512 blocks, 256 threads. Block (b,i,ch) reduces a
// 32-row x 1024-float column strip into 32 pooled cols x 16 ch.
__global__ __launch_bounds__(256) void pool_kernel(const float* __restrict__ fm,
                                                   float* __restrict__ P) {
    int blk = blockIdx.x;
    int ch = blk & (CH - 1);
    int bi = blk >> 3;               // b*NP + i  (since H = NP*PH)
    int t = threadIdx.x;
    const float4* src = (const float4*)fm + (size_t)bi * (PH * W * C / 4) + ch * 256 + t;
    float4 acc = make_float4(0.f, 0.f, 0.f, 0.f);
#pragma unroll 8
    for (int hh = 0; hh < PH; ++hh) {
        float4 v = src[hh * (W * C / 4)];
        acc.x += v.x; acc.y += v.y; acc.z += v.z; acc.w += v.w;
    }
    __shared__ float4 s[256];
    s[t] = acc;
    __syncthreads();
    if (t < 128) {
        int u = t >> 2, q = t & 3;        // pooled-pixel-local, channel quad
        float4 a = s[u * 8 + q], b2 = s[u * 8 + 4 + q];
        float4 r = make_float4((a.x + b2.x) * (1.0f / 64.0f),
                               (a.y + b2.y) * (1.0f / 64.0f),
                               (a.z + b2.z) * (1.0f / 64.0f),
                               (a.w + b2.w) * (1.0f / 64.0f));
        float4* out = (float4*)(P + (size_t)bi * (W2 * C)) + ch * 128 + t;
        *out = r;
    }
}

// ---------------- Kernel 2: masked 5x5 conv (rows 0,4 only), row + col ----
// grid = B*NP blocks, 512 threads. t<256: row_op for j=t. t>=256: col_op.
__global__ __launch_bounds__(512) void conv_kernel(const float* __restrict__ P,
                                                   const float* __restrict__ kern,
                                                   const float* __restrict__ bias,
                                                   float* __restrict__ ROW,
                                                   float* __restrict__ COL) {
    int blk = blockIdx.x;
    int b = blk >> 3, i = blk & 7;
    int t = threadIdx.x;
    __shared__ float K0[5 * C * FIL];    // kernel row r=0
    __shared__ float K4[5 * C * FIL];    // kernel row r=4
    for (int idx = t; idx < 5 * C * FIL; idx += 512) {
        K0[idx] = kern[idx];                     // r=0 at offset 0
        K4[idx] = kern[4 * 5 * C * FIL + idx];   // r=4
    }
    __syncthreads();
    int j = t & 255;
    const float* Pb = P + (size_t)b * (NP * W2 * C);
    float acc[FIL];
#pragma unroll
    for (int f = 0; f < FIL; ++f) acc[f] = bias[f];

    if (t < 256) {
        // row_op: rows i-2, i+2 of pooled; cols j+s-2; K[rr][s]
#pragma unroll
        for (int rr = 0; rr < 2; ++rr) {
            int ii = i + (rr ? 2 : -2);
            if (ii < 0 || ii >= NP) continue;
            const float* Kr = rr ? K4 : K0;
            for (int s = 0; s < 5; ++s) {
                int jj = j + s - 2;
                if (jj < 0 || jj >= W2) continue;
                const float* p = Pb + (size_t)(ii * W2 + jj) * C;
                for (int c = 0; c < C; ++c) {
                    float pv = p[c];
                    const float* kk = Kr + (s * C + c) * FIL;
#pragma unroll
                    for (int f = 0; f < FIL; ++f) acc[f] = fmaf(pv, kk[f], acc[f]);
                }
            }
        }
        float* o = ROW + ((size_t)(b * NP + i) * W2 + j) * FIL;
#pragma unroll
        for (int f = 0; f < FIL; ++f) o[f] = fmaxf(acc[f], 0.0f);
    } else {
        // col_op: rows i+s-2; cols j-2, j+2; K[rr][s]
        for (int s = 0; s < 5; ++s) {
            int ii = i + s - 2;
            if (ii < 0 || ii >= NP) continue;
#pragma unroll
            for (int rr = 0; rr < 2; ++rr) {
                int jj = j + (rr ? 2 : -2);
                if (jj < 0 || jj >= W2) continue;
                const float* Kr = rr ? K4 : K0;
                const float* p = Pb + (size_t)(ii * W2 + jj) * C;
                for (int c = 0; c < C; ++c) {
                    float pv = p[c];
                    const float* kk = Kr + (s * C + c) * FIL;
#pragma unroll
                    for (int f = 0; f < FIL; ++f) acc[f] = fmaf(pv, kk[f], acc[f]);
                }
            }
        }
        float* o = COL + ((size_t)(b * NP + i) * W2 + j) * FIL;
#pragma unroll
        for (int f = 0; f < FIL; ++f) o[f] = fmaxf(acc[f], 0.0f);
    }
}

// ---------------- Kernel 3: bilinear upsample + diff + concat -------------
// grid = B*H blocks, 256 threads; one output row [W][48] per block.
// Output is write-once -> nontemporal stores (keep fm resident in L3).
__global__ __launch_bounds__(256) void up_kernel(const float* __restrict__ fm,
                                                 const float* __restrict__ ROW,
                                                 const float* __restrict__ COL,
                                                 float* __restrict__ out) {
    int blk = blockIdx.x;
    int b = blk >> 8, h = blk & 255;
    int t = threadIdx.x;
    __shared__ float Rs[W2 * C];   // H-lerped row_op row
    __shared__ float Cs[W2 * C];   // H-lerped col_op row

    float sh = (h + 0.5f) * (1.0f / 32.0f) - 0.5f;
    float flh = floorf(sh);
    float fh = sh - flh;
    int i0 = (int)flh;
    int i1 = min(i0 + 1, NP - 1);
    i0 = max(i0, 0);
    float wa = 1.0f - fh, wb = fh;

    const float4* r0 = (const float4*)(ROW + (size_t)(b * NP + i0) * (W2 * C));
    const float4* r1 = (const float4*)(ROW + (size_t)(b * NP + i1) * (W2 * C));
    const float4* c0 = (const float4*)(COL + (size_t)(b * NP + i0) * (W2 * C));
    const float4* c1 = (const float4*)(COL + (size_t)(b * NP + i1) * (W2 * C));
#pragma unroll
    for (int k = 0; k < 4; ++k) {
        int idx = t + k * 256;
        float4 a = r0[idx], bv = r1[idx];
        ((float4*)Rs)[idx] = make_float4(wa * a.x + wb * bv.x, wa * a.y + wb * bv.y,
                                         wa * a.z + wb * bv.z, wa * a.w + wb * bv.w);
        float4 ca = c0[idx], cb = c1[idx];
        ((float4*)Cs)[idx] = make_float4(wa * ca.x + wb * cb.x, wa * ca.y + wb * cb.y,
                                         wa * ca.z + wb * cb.z, wa * ca.w + wb * cb.w);
    }
    __syncthreads();

    const float4* fmr = (const float4*)(fm + (size_t)(b * H + h) * (W * C));
    f32x4* orow = (f32x4*)(out + (size_t)(b * H + h) * (W * 48));
    for (int slot = t; slot < W * 12; slot += 256) {
        int p = slot / 12;
        int q = slot - p * 12;
        int cc = (q & 3) * 4;
        float4 v = fmr[p * 4 + (q & 3)];
        if (q >= 4) {
            float sw = 0.5f * p - 0.25f;
            float flw = floorf(sw);
            float fw = sw - flw;
            int j0i = max((int)flw, 0);
            int j1i = min((int)flw + 1, W2 - 1);
            const float* S = (q < 8) ? Rs : Cs;
            const float* A  = S + j0i * 16 + cc;
            const float* Bv = S + j1i * 16 + cc;
            float iw = 1.0f - fw;
            v.x -= iw * A[0] + fw * Bv[0];
            v.y -= iw * A[1] + fw * Bv[1];
            v.z -= iw * A[2] + fw * Bv[2];
            v.w -= iw * A[3] + fw * Bv[3];
        }
        f32x4 vv = { v.x, v.y, v.z, v.w };
        __builtin_nontemporal_store(vv, &orow[slot]);
    }
}

extern "C" void kernel_launch(void* const* d_in, const int* in_sizes, int n_in,
                              void* d_out, int out_size, void* d_ws, size_t ws_size,
                              hipStream_t stream) {
    const float* fm   = (const float*)d_in[0];
    const float* kern = (const float*)d_in[1];
    const float* bias = (const float*)d_in[2];
    float* out = (float*)d_out;
    float* P   = (float*)d_ws;
    float* ROW = P + POOL_ELEMS;
    float* COL = ROW + POOL_ELEMS;

    pool_kernel<<<B * NP * CH, 256, 0, stream>>>(fm, P);
    conv_kernel<<<B * NP, 512, 0, stream>>>(P, kern, bias, ROW, COL);
    up_kernel<<<B * H, 256, 0, stream>>>(fm, ROW, COL, out);
}

// Round 4
// 66.483 us; speedup vs baseline: 1.2507x; 1.0874x over previous
//
#include <hip/hip_runtime.h>

#define B 8
#define H 256
#define W 512
#define C 16
#define FIL 16
#define NP 8
#define PH 32      // H/NP
#define W2 256     // W/2
#define CH 8       // width chunks for pool kernel
#define POOL_ELEMS (B*NP*W2*C)   // 327680 floats

typedef float f32x4 __attribute__((ext_vector_type(4)));

// ---------------- Kernel 1: average pool (32x2) ----------------
// grid = B*NP*CH = 512 blocks, 256 threads. Block (b,i,ch) reduces a
// 32-row x 1024-float column strip into 32 pooled cols x 16 ch.
__global__ __launch_bounds__(256) void pool_kernel(const float* __restrict__ fm,
                                                   float* __restrict__ P) {
    int blk = blockIdx.x;
    int ch = blk & (CH - 1);
    int bi = blk >> 3;               // b*NP + i  (since H = NP*PH)
    int t = threadIdx.x;
    const float4* src = (const float4*)fm + (size_t)bi * (PH * W * C / 4) + ch * 256 + t;
    float4 acc = make_float4(0.f, 0.f, 0.f, 0.f);
#pragma unroll 8
    for (int hh = 0; hh < PH; ++hh) {
        float4 v = src[hh * (W * C / 4)];
        acc.x += v.x; acc.y += v.y; acc.z += v.z; acc.w += v.w;
    }
    __shared__ float4 s[256];
    s[t] = acc;
    __syncthreads();
    if (t < 128) {
        int u = t >> 2, q = t & 3;        // pooled-pixel-local, channel quad
        float4 a = s[u * 8 + q], b2 = s[u * 8 + 4 + q];
        float4 r = make_float4((a.x + b2.x) * (1.0f / 64.0f),
                               (a.y + b2.y) * (1.0f / 64.0f),
                               (a.z + b2.z) * (1.0f / 64.0f),
                               (a.w + b2.w) * (1.0f / 64.0f));
        float4* out = (float4*)(P + (size_t)bi * (W2 * C)) + ch * 128 + t;
        *out = r;
    }
}

// ---------------- Kernel 2: masked 5x5 conv (rows 0,4 only), row + col ----
// grid = B*NP*4 = 256 blocks, 256 threads.
// part = blk&3: 0,1 -> row_op (j-half 0,1); 2,3 -> col_op (j-half 0,1).
// thread t: j = jhalf*128 + (t>>1); filter half fh = t&1 (8 filters).
__global__ __launch_bounds__(256) void conv_kernel(const float* __restrict__ P,
                                                   const float* __restrict__ kern,
                                                   const float* __restrict__ bias,
                                                   float* __restrict__ ROW,
                                                   float* __restrict__ COL) {
    int blk = blockIdx.x;
    int part = blk & 3;
    int bi = blk >> 2;
    int b = bi >> 3, i = bi & 7;
    int t = threadIdx.x;
    __shared__ float K0[5 * C * FIL];    // kernel row r=0
    __shared__ float K4[5 * C * FIL];    // kernel row r=4
    for (int idx = t; idx < 5 * C * FIL; idx += 256) {
        K0[idx] = kern[idx];                     // r=0 at offset 0
        K4[idx] = kern[4 * 5 * C * FIL + idx];   // r=4
    }
    __syncthreads();
    bool is_row = (part < 2);
    int jhalf = part & 1;
    int j = jhalf * 128 + (t >> 1);
    int fh = (t & 1) * 8;
    const float* Pb = P + (size_t)b * (NP * W2 * C);
    float acc[8];
#pragma unroll
    for (int f = 0; f < 8; ++f) acc[f] = bias[fh + f];

    if (is_row) {
        // row_op: rows i-2 (K0), i+2 (K4); cols j+s-2
#pragma unroll
        for (int rr = 0; rr < 2; ++rr) {
            int ii = i + (rr ? 2 : -2);
            if (ii < 0 || ii >= NP) continue;
            const float* Kr = (rr ? K4 : K0) + fh;
            for (int s = 0; s < 5; ++s) {
                int jj = j + s - 2;
                if (jj < 0 || jj >= W2) continue;
                const float4* p4 = (const float4*)(Pb + (size_t)(ii * W2 + jj) * C);
#pragma unroll
                for (int cq = 0; cq < 4; ++cq) {
                    float4 pv = p4[cq];
                    const float* kk = Kr + (s * C + cq * 4) * FIL;
#pragma unroll
                    for (int f = 0; f < 8; ++f) {
                        acc[f] = fmaf(pv.x, kk[f], acc[f]);
                        acc[f] = fmaf(pv.y, kk[FIL + f], acc[f]);
                        acc[f] = fmaf(pv.z, kk[2 * FIL + f], acc[f]);
                        acc[f] = fmaf(pv.w, kk[3 * FIL + f], acc[f]);
                    }
                }
            }
        }
        float* o = ROW + ((size_t)(b * NP + i) * W2 + j) * FIL + fh;
#pragma unroll
        for (int f = 0; f < 8; ++f) o[f] = fmaxf(acc[f], 0.0f);
    } else {
        // col_op: rows i+s-2; cols j-2 (K0), j+2 (K4)
        for (int s = 0; s < 5; ++s) {
            int ii = i + s - 2;
            if (ii < 0 || ii >= NP) continue;
#pragma unroll
            for (int rr = 0; rr < 2; ++rr) {
                int jj = j + (rr ? 2 : -2);
                if (jj < 0 || jj >= W2) continue;
                const float* Kr = (rr ? K4 : K0) + fh;
                const float4* p4 = (const float4*)(Pb + (size_t)(ii * W2 + jj) * C);
#pragma unroll
                for (int cq = 0; cq < 4; ++cq) {
                    float4 pv = p4[cq];
                    const float* kk = Kr + (s * C + cq * 4) * FIL;
#pragma unroll
                    for (int f = 0; f < 8; ++f) {
                        acc[f] = fmaf(pv.x, kk[f], acc[f]);
                        acc[f] = fmaf(pv.y, kk[FIL + f], acc[f]);
                        acc[f] = fmaf(pv.z, kk[2 * FIL + f], acc[f]);
                        acc[f] = fmaf(pv.w, kk[3 * FIL + f], acc[f]);
                    }
                }
            }
        }
        float* o = COL + ((size_t)(b * NP + i) * W2 + j) * FIL + fh;
#pragma unroll
        for (int f = 0; f < 8; ++f) o[f] = fmaxf(acc[f], 0.0f);
    }
}

// ---------------- Kernel 3: bilinear upsample + diff + concat -------------
// grid = B*H blocks, 384 threads (= 32 pixels x 12 slots); one output row
// [W][48] per block. p_local/q hoisted out of the store loop (no /12 inside).
__global__ __launch_bounds__(384) void up_kernel(const float* __restrict__ fm,
                                                 const float* __restrict__ ROW,
                                                 const float* __restrict__ COL,
                                                 float* __restrict__ out) {
    int blk = blockIdx.x;
    int b = blk >> 8, h = blk & 255;
    int t = threadIdx.x;
    __shared__ float Rs[W2 * C];   // H-lerped row_op row
    __shared__ float Cs[W2 * C];   // H-lerped col_op row

    float sh = (h + 0.5f) * (1.0f / 32.0f) - 0.5f;
    float flh = floorf(sh);
    float fh = sh - flh;
    int i0 = (int)flh;
    int i1 = min(i0 + 1, NP - 1);
    i0 = max(i0, 0);
    float wa = 1.0f - fh, wb = fh;

    const float4* r0 = (const float4*)(ROW + (size_t)(b * NP + i0) * (W2 * C));
    const float4* r1 = (const float4*)(ROW + (size_t)(b * NP + i1) * (W2 * C));
    const float4* c0 = (const float4*)(COL + (size_t)(b * NP + i0) * (W2 * C));
    const float4* c1 = (const float4*)(COL + (size_t)(b * NP + i1) * (W2 * C));
    for (int idx = t; idx < W2 * C / 4; idx += 384) {
        float4 a = r0[idx], bv = r1[idx];
        ((float4*)Rs)[idx] = make_float4(wa * a.x + wb * bv.x, wa * a.y + wb * bv.y,
                                         wa * a.z + wb * bv.z, wa * a.w + wb * bv.w);
        float4 ca = c0[idx], cb = c1[idx];
        ((float4*)Cs)[idx] = make_float4(wa * ca.x + wb * cb.x, wa * ca.y + wb * cb.y,
                                         wa * ca.z + wb * cb.z, wa * ca.w + wb * cb.w);
    }
    __syncthreads();

    int p_local = t / 12;          // 0..31, computed once
    int q = t - p_local * 12;      // 0..11, fixed per thread
    int cc = (q & 3) * 4;
    bool is_copy = (q < 4);
    const float* S = (q < 8) ? Rs : Cs;

    const float4* fmr = (const float4*)(fm + (size_t)(b * H + h) * (W * C));
    f32x4* orow = (f32x4*)(out + (size_t)(b * H + h) * (W * 48));
#pragma unroll
    for (int k = 0; k < 16; ++k) {
        int p = k * 32 + p_local;
        float4 v = fmr[p * 4 + (q & 3)];
        if (!is_copy) {
            float sw = 0.5f * p - 0.25f;
            float flw = floorf(sw);
            float fw = sw - flw;
            int j0i = max((int)flw, 0);
            int j1i = min((int)flw + 1, W2 - 1);
            const float* A  = S + j0i * 16 + cc;
            const float* Bv = S + j1i * 16 + cc;
            float iw = 1.0f - fw;
            v.x -= iw * A[0] + fw * Bv[0];
            v.y -= iw * A[1] + fw * Bv[1];
            v.z -= iw * A[2] + fw * Bv[2];
            v.w -= iw * A[3] + fw * Bv[3];
        }
        f32x4 vv = { v.x, v.y, v.z, v.w };
        __builtin_nontemporal_store(vv, &orow[(size_t)p * 12 + q]);
    }
}

extern "C" void kernel_launch(void* const* d_in, const int* in_sizes, int n_in,
                              void* d_out, int out_size, void* d_ws, size_t ws_size,
                              hipStream_t stream) {
    const float* fm   = (const float*)d_in[0];
    const float* kern = (const float*)d_in[1];
    const float* bias = (const float*)d_in[2];
    float* out = (float*)d_out;
    float* P   = (float*)d_ws;
    float* ROW = P + POOL_ELEMS;
    float* COL = ROW + POOL_ELEMS;

    pool_kernel<<<B * NP * CH, 256, 0, stream>>>(fm, P);
    conv_kernel<<<B * NP * 4, 256, 0, stream>>>(P, kern, bias, ROW, COL);
    up_kernel<<<B * H, 384, 0, stream>>>(fm, ROW, COL, out);
}